// Round 2
// baseline (693.233 us; speedup 1.0000x reference)
//
#include <hip/hip_runtime.h>

#define N_NODES 100000
#define N_EDGES 3200000
#define D_FEAT 128
#define HIDDEN 16
#define NCLS 8
#define NB_SCAN ((N_NODES + 255) / 256)   // 391 blocks

// -------- workspace layout (32-bit words) --------
// deg  (uint)  [0, N)            edge-only in-degree
// dis  (float) [N, 2N)           rsqrt(deg+1)
// rp   (uint)  [2N, 3N)          exclusive bucket starts -> bucket ENDS after fill
// bsum (uint)  [3N, 3N+512)      scan block sums
// csr  (uint)  [3N+512, +E)      src ids bucketed by dst
// hd1  (float) [b1, +16N)        dis * (x @ W1)
// hd2  (float) [b2, +8N)         dis * (relu(dis*agg1+b1) @ W2)

__global__ void k_deg_init(unsigned* __restrict__ deg) {
    int i = blockIdx.x * blockDim.x + threadIdx.x;
    if (i < N_NODES) deg[i] = 0u;
}

__global__ void k_deg_count(const int* __restrict__ dst, unsigned* __restrict__ deg) {
    int i = blockIdx.x * blockDim.x + threadIdx.x;
    if (i < N_EDGES) atomicAdd(&deg[dst[i]], 1u);
}

__global__ void k_dis(const unsigned* __restrict__ deg, float* __restrict__ dis) {
    int i = blockIdx.x * blockDim.x + threadIdx.x;
    if (i < N_NODES) dis[i] = rsqrtf((float)(deg[i] + 1u));   // +1 self-loop
}

// ---- exclusive prefix scan of deg -> rp (3 kernels) ----
__global__ void k_scan1(const unsigned* __restrict__ deg, unsigned* __restrict__ rp,
                        unsigned* __restrict__ bsum) {
    __shared__ unsigned s[256];
    int tid = threadIdx.x;
    int i = blockIdx.x * 256 + tid;
    unsigned v = (i < N_NODES) ? deg[i] : 0u;
    s[tid] = v; __syncthreads();
    for (int off = 1; off < 256; off <<= 1) {
        unsigned t = (tid >= off) ? s[tid - off] : 0u;
        __syncthreads();
        s[tid] += t;
        __syncthreads();
    }
    if (i < N_NODES) rp[i] = s[tid] - v;          // exclusive
    if (tid == 255) bsum[blockIdx.x] = s[255];
}

__global__ void k_scan2(unsigned* __restrict__ bsum) {
    __shared__ unsigned s[512];
    int tid = threadIdx.x;
    unsigned v = (tid < NB_SCAN) ? bsum[tid] : 0u;
    s[tid] = v; __syncthreads();
    for (int off = 1; off < 512; off <<= 1) {
        unsigned t = (tid >= off) ? s[tid - off] : 0u;
        __syncthreads();
        s[tid] += t;
        __syncthreads();
    }
    bsum[tid] = s[tid] - v;                        // exclusive
}

__global__ void k_scan3(unsigned* __restrict__ rp, const unsigned* __restrict__ bsum) {
    int i = blockIdx.x * blockDim.x + threadIdx.x;
    if (i < N_NODES) rp[i] += bsum[i >> 8];
}

// place src ids into dst buckets; rp[i] becomes bucket END
__global__ void k_csr_fill(const int* __restrict__ src, const int* __restrict__ dst,
                           unsigned* __restrict__ rp, unsigned* __restrict__ csr) {
    int e = blockIdx.x * blockDim.x + threadIdx.x;
    if (e < N_EDGES) {
        unsigned p = atomicAdd(&rp[dst[e]], 1u);
        csr[p] = (unsigned)src[e];
    }
}

// hd1 = dis[node] * (x @ W1)
__global__ __launch_bounds__(256) void k_gemm1(const float* __restrict__ x,
                                               const float* __restrict__ W1,
                                               const float* __restrict__ dis,
                                               float* __restrict__ hd1) {
    __shared__ float sW[D_FEAT * HIDDEN];   // 8 KB  [k][j]
    __shared__ float sx[64][132];           // pad breaks bank conflicts
    int tid = threadIdx.x;
    for (int t = tid; t < D_FEAT * HIDDEN; t += 256) sW[t] = W1[t];

    int node0 = blockIdx.x * 64;
    #pragma unroll
    for (int it = 0; it < 8; ++it) {
        int lin = it * 256 + tid;
        int r   = lin >> 5;
        int c4  = lin & 31;
        int row = node0 + r;
        float4 v = make_float4(0.f, 0.f, 0.f, 0.f);
        if (row < N_NODES)
            v = *(const float4*)(x + (size_t)row * D_FEAT + c4 * 4);
        *(float4*)(&sx[r][c4 * 4]) = v;
    }
    __syncthreads();

    int lr   = tid >> 2;
    int node = node0 + lr;
    int f0   = (tid & 3) * 4;
    if (node >= N_NODES) return;

    float a0 = 0.f, a1 = 0.f, a2 = 0.f, a3 = 0.f;
    #pragma unroll
    for (int k = 0; k < D_FEAT; ++k) {
        float xv = sx[lr][k];
        a0 += xv * sW[k * HIDDEN + f0 + 0];
        a1 += xv * sW[k * HIDDEN + f0 + 1];
        a2 += xv * sW[k * HIDDEN + f0 + 2];
        a3 += xv * sW[k * HIDDEN + f0 + 3];
    }
    float s = dis[node];
    *(float4*)(hd1 + (size_t)node * HIDDEN + f0) = make_float4(a0 * s, a1 * s, a2 * s, a3 * s);
}

// gather layer1 + fused relu/bias + @W2: writes hd2 = dis*(relu(dis*agg+b1)@W2)
__global__ __launch_bounds__(256) void k_gather16_l2(
        const unsigned* __restrict__ rp, const unsigned* __restrict__ csr,
        const float* __restrict__ hd1, const float* __restrict__ dis,
        const float* __restrict__ b1, const float* __restrict__ W2,
        float* __restrict__ hd2) {
    __shared__ float sh[16][17];
    __shared__ float sW2[HIDDEN * NCLS];
    __shared__ float sb1[HIDDEN];
    int tid = threadIdx.x;
    if (tid < HIDDEN * NCLS) sW2[tid] = W2[tid];
    if (tid < HIDDEN)        sb1[tid] = b1[tid];

    int n = tid >> 4;                 // 16 nodes per block
    int j = tid & 15;
    int node = blockIdx.x * 16 + n;   // 6250 * 16 == 100000 exact

    unsigned start = (node == 0) ? 0u : rp[node - 1];  // rp holds bucket ends
    unsigned end   = rp[node];
    float acc = hd1[(size_t)node * HIDDEN + j];        // self-loop
    for (unsigned e = start; e < end; ++e) {
        unsigned s = csr[e];
        acc += hd1[(size_t)s * HIDDEN + j];
    }
    float dv = dis[node];
    __syncthreads();                                   // sW2/sb1 visible
    float h = fmaxf(dv * acc + sb1[j], 0.f);
    sh[n][j] = h;
    __syncthreads();
    if (j < NCLS) {
        float o = 0.f;
        #pragma unroll
        for (int m = 0; m < HIDDEN; ++m) o += sh[n][m] * sW2[m * NCLS + j];
        hd2[(size_t)node * NCLS + j] = dv * o;
    }
}

// gather layer2 + bias + log_softmax (8 lanes per node)
__global__ __launch_bounds__(256) void k_gather8_final(
        const unsigned* __restrict__ rp, const unsigned* __restrict__ csr,
        const float* __restrict__ hd2, const float* __restrict__ dis,
        const float* __restrict__ b2, float* __restrict__ out) {
    int tid = threadIdx.x;
    int node = blockIdx.x * 32 + (tid >> 3);  // 3125 * 32 == 100000 exact
    int j = tid & 7;

    unsigned start = (node == 0) ? 0u : rp[node - 1];
    unsigned end   = rp[node];
    float acc = hd2[(size_t)node * NCLS + j];          // self-loop
    for (unsigned e = start; e < end; ++e)
        acc += hd2[(size_t)csr[e] * NCLS + j];

    float l = dis[node] * acc + b2[j];
    float m = l;
    m = fmaxf(m, __shfl_xor(m, 1, 8));
    m = fmaxf(m, __shfl_xor(m, 2, 8));
    m = fmaxf(m, __shfl_xor(m, 4, 8));
    float ex = __expf(l - m);
    float ssum = ex;
    ssum += __shfl_xor(ssum, 1, 8);
    ssum += __shfl_xor(ssum, 2, 8);
    ssum += __shfl_xor(ssum, 4, 8);
    out[(size_t)node * NCLS + j] = l - (logf(ssum) + m);
}

extern "C" void kernel_launch(void* const* d_in, const int* in_sizes, int n_in,
                              void* d_out, int out_size, void* d_ws, size_t ws_size,
                              hipStream_t stream) {
    const float* x  = (const float*)d_in[0];
    const int*   ei = (const int*)d_in[1];      // [2, E]: row0 = src, row1 = dst
    const float* W1 = (const float*)d_in[2];
    const float* b1 = (const float*)d_in[3];
    const float* W2 = (const float*)d_in[4];
    const float* b2 = (const float*)d_in[5];
    float* out = (float*)d_out;

    const int* src = ei;
    const int* dst = ei + N_EDGES;

    unsigned* ws = (unsigned*)d_ws;
    const size_t N = N_NODES;
    unsigned* deg  = ws;
    float*    dis  = (float*)(ws + N);
    unsigned* rp   = ws + 2 * N;
    unsigned* bsum = ws + 3 * N;
    unsigned* csr  = ws + 3 * N + 512;
    float*    hd1  = (float*)(ws + 3 * N + 512 + N_EDGES);
    float*    hd2  = hd1 + 16 * N;

    const int TB = 256;
    int nb_nodes = (N_NODES + TB - 1) / TB;
    int nb_edges = (N_EDGES + TB - 1) / TB;

    k_deg_init<<<nb_nodes, TB, 0, stream>>>(deg);
    k_deg_count<<<nb_edges, TB, 0, stream>>>(dst, deg);
    k_dis<<<nb_nodes, TB, 0, stream>>>(deg, dis);

    k_scan1<<<NB_SCAN, 256, 0, stream>>>(deg, rp, bsum);
    k_scan2<<<1, 512, 0, stream>>>(bsum);
    k_scan3<<<nb_nodes, TB, 0, stream>>>(rp, bsum);
    k_csr_fill<<<nb_edges, TB, 0, stream>>>(src, dst, rp, csr);

    k_gemm1<<<(N_NODES + 63) / 64, TB, 0, stream>>>(x, W1, dis, hd1);

    k_gather16_l2<<<N_NODES / 16, TB, 0, stream>>>(rp, csr, hd1, dis, b1, W2, hd2);
    k_gather8_final<<<N_NODES / 32, TB, 0, stream>>>(rp, csr, hd2, dis, b2, out);
}

// Round 3
// 597.874 us; speedup vs baseline: 1.1595x; 1.1595x over previous
//
#include <hip/hip_runtime.h>

#define N_NODES 100000
#define N_EDGES 3200000
#define D_FEAT 128
#define HIDDEN 16
#define NCLS 8

#define NBKT 256            // coarse dst buckets
#define BSZ  391            // nodes per bucket (256*391 >= 100000)
#define CHUNK 8192          // edges per hist/fill block
#define NCHUNK 391          // ceil(E/CHUNK): 391*8192 >= 3.2M
#define TOTH (NBKT * NCHUNK)   // 100096 = 391*256 exactly
#define NBS1 (TOTH / 256)      // 391

// -------- workspace layout (32-bit words) --------
// dis  (float) [0, N)
// hist (uint)  [N, N+TOTH)      per (bucket,chunk) counts -> exclusive prefix
// bsum (uint)  [+512)
// rec  (uint)  [+E)             (src<<9)|dst_local, bucketed by dst
// hd1  (float) [+16N)           dis * (x @ W1)
// hd2  (float) [+8N)            dis * (relu(dis*agg1+b1) @ W2)

// per-chunk histogram of dst buckets
__global__ __launch_bounds__(256) void k_hist(const int* __restrict__ dst,
                                              unsigned* __restrict__ hist) {
    __shared__ unsigned h[NBKT];
    int tid = threadIdx.x;
    h[tid] = 0u;
    __syncthreads();
    int base = blockIdx.x * CHUNK;
    #pragma unroll
    for (int it = 0; it < CHUNK / 256; ++it) {
        int e = base + it * 256 + tid;
        if (e < N_EDGES) atomicAdd(&h[dst[e] / BSZ], 1u);
    }
    __syncthreads();
    hist[(unsigned)tid * NCHUNK + blockIdx.x] = h[tid];   // bucket-major layout
}

// ---- exclusive prefix scan over hist (flattened bucket-major), 3 kernels ----
__global__ void k_scan1(unsigned* __restrict__ a, unsigned* __restrict__ bsum) {
    __shared__ unsigned s[256];
    int tid = threadIdx.x;
    int i = blockIdx.x * 256 + tid;
    unsigned v = a[i];                       // TOTH == grid*256 exactly
    s[tid] = v; __syncthreads();
    for (int off = 1; off < 256; off <<= 1) {
        unsigned t = (tid >= off) ? s[tid - off] : 0u;
        __syncthreads();
        s[tid] += t;
        __syncthreads();
    }
    a[i] = s[tid] - v;                       // exclusive
    if (tid == 255) bsum[blockIdx.x] = s[255];
}

__global__ void k_scan2(unsigned* __restrict__ bsum) {
    __shared__ unsigned s[512];
    int tid = threadIdx.x;
    unsigned v = (tid < NBS1) ? bsum[tid] : 0u;
    s[tid] = v; __syncthreads();
    for (int off = 1; off < 512; off <<= 1) {
        unsigned t = (tid >= off) ? s[tid - off] : 0u;
        __syncthreads();
        s[tid] += t;
        __syncthreads();
    }
    bsum[tid] = s[tid] - v;                  // exclusive
}

__global__ void k_scan3(unsigned* __restrict__ a, const unsigned* __restrict__ bsum) {
    int i = blockIdx.x * blockDim.x + threadIdx.x;
    a[i] += bsum[i >> 8];
}

// place packed edge records into exact slots; LDS cursors only (no global atomics)
__global__ __launch_bounds__(256) void k_fill(const int* __restrict__ src,
                                              const int* __restrict__ dst,
                                              const unsigned* __restrict__ hist,
                                              unsigned* __restrict__ rec) {
    __shared__ unsigned cur[NBKT];
    int tid = threadIdx.x;
    cur[tid] = hist[(unsigned)tid * NCHUNK + blockIdx.x];
    __syncthreads();
    int base = blockIdx.x * CHUNK;
    #pragma unroll
    for (int it = 0; it < CHUNK / 256; ++it) {
        int e = base + it * 256 + tid;
        if (e < N_EDGES) {
            int d = dst[e];
            int b = d / BSZ;
            unsigned p = atomicAdd(&cur[b], 1u);
            rec[p] = ((unsigned)src[e] << 9) | (unsigned)(d - b * BSZ);
        }
    }
}

// per-bucket degree count from records (LDS atomics) -> dis = rsqrt(deg+1)
__global__ __launch_bounds__(1024) void k_dis2(const unsigned* __restrict__ hist,
                                               const unsigned* __restrict__ rec,
                                               float* __restrict__ dis) {
    __shared__ unsigned cnt[BSZ];
    int tid = threadIdx.x;
    int bkt = blockIdx.x;
    int node0 = bkt * BSZ;
    int nn = (node0 + BSZ <= N_NODES) ? BSZ : (N_NODES - node0);
    for (int n = tid; n < nn; n += 1024) cnt[n] = 1u;   // self-loop
    __syncthreads();
    unsigned start = hist[(unsigned)bkt * NCHUNK];
    unsigned end = (bkt == NBKT - 1) ? N_EDGES : hist[(unsigned)(bkt + 1) * NCHUNK];
    for (unsigned e = start + tid; e < end; e += 1024)
        atomicAdd(&cnt[rec[e] & 511u], 1u);
    __syncthreads();
    for (int n = tid; n < nn; n += 1024)
        dis[node0 + n] = rsqrtf((float)cnt[n]);
}

// hd1 = dis[node] * (x @ W1)
__global__ __launch_bounds__(256) void k_gemm1(const float* __restrict__ x,
                                               const float* __restrict__ W1,
                                               const float* __restrict__ dis,
                                               float* __restrict__ hd1) {
    __shared__ float sW[D_FEAT * HIDDEN];   // 8 KB  [k][j]
    __shared__ float sx[64][132];
    int tid = threadIdx.x;
    for (int t = tid; t < D_FEAT * HIDDEN; t += 256) sW[t] = W1[t];

    int node0 = blockIdx.x * 64;
    #pragma unroll
    for (int it = 0; it < 8; ++it) {
        int lin = it * 256 + tid;
        int r   = lin >> 5;
        int c4  = lin & 31;
        int row = node0 + r;
        float4 v = make_float4(0.f, 0.f, 0.f, 0.f);
        if (row < N_NODES)
            v = *(const float4*)(x + (size_t)row * D_FEAT + c4 * 4);
        *(float4*)(&sx[r][c4 * 4]) = v;
    }
    __syncthreads();

    int lr   = tid >> 2;
    int node = node0 + lr;
    int f0   = (tid & 3) * 4;
    if (node >= N_NODES) return;

    float a0 = 0.f, a1 = 0.f, a2 = 0.f, a3 = 0.f;
    #pragma unroll
    for (int k = 0; k < D_FEAT; ++k) {
        float xv = sx[lr][k];
        a0 += xv * sW[k * HIDDEN + f0 + 0];
        a1 += xv * sW[k * HIDDEN + f0 + 1];
        a2 += xv * sW[k * HIDDEN + f0 + 2];
        a3 += xv * sW[k * HIDDEN + f0 + 3];
    }
    float s = dis[node];
    *(float4*)(hd1 + (size_t)node * HIDDEN + f0) = make_float4(a0 * s, a1 * s, a2 * s, a3 * s);
}

// layer1 aggregation in LDS + fused bias/relu/@W2 -> hd2
__global__ __launch_bounds__(1024) void k_aggB(const unsigned* __restrict__ hist,
                                               const unsigned* __restrict__ rec,
                                               const float* __restrict__ hd1,
                                               const float* __restrict__ dis,
                                               const float* __restrict__ b1,
                                               const float* __restrict__ W2,
                                               float* __restrict__ hd2) {
    __shared__ float acc[BSZ][HIDDEN + 1];  // 26.6 KB, pad 17 breaks conflicts
    __shared__ float sW2[HIDDEN * NCLS];
    __shared__ float sb1[HIDDEN];
    int tid = threadIdx.x;
    int bkt = blockIdx.x;
    int node0 = bkt * BSZ;
    int nn = (node0 + BSZ <= N_NODES) ? BSZ : (N_NODES - node0);
    if (tid < HIDDEN * NCLS) sW2[tid] = W2[tid];
    if (tid < HIDDEN)        sb1[tid] = b1[tid];

    int j = tid & 15, rr = tid >> 4;        // 64 edge-slots x 16 feat lanes
    for (int r = rr; r < nn; r += 64)
        acc[r][j] = hd1[(size_t)(node0 + r) * HIDDEN + j];   // self-loop init
    __syncthreads();

    unsigned start = hist[(unsigned)bkt * NCHUNK];
    unsigned end = (bkt == NBKT - 1) ? N_EDGES : hist[(unsigned)(bkt + 1) * NCHUNK];
    for (unsigned e = start + rr; e < end; e += 64) {
        unsigned r = rec[e];
        unsigned s = r >> 9, dl = r & 511u;
        float v = hd1[(size_t)s * HIDDEN + j];
        atomicAdd(&acc[dl][j], v);
    }
    __syncthreads();

    // epilogue: thread-per-node
    for (int n = tid; n < nn; n += 1024) {
        int node = node0 + n;
        float dv = dis[node];
        float hbuf[HIDDEN];
        #pragma unroll
        for (int m = 0; m < HIDDEN; ++m)
            hbuf[m] = fmaxf(dv * acc[n][m] + sb1[m], 0.f);
        float o[NCLS];
        #pragma unroll
        for (int k = 0; k < NCLS; ++k) {
            float t = 0.f;
            #pragma unroll
            for (int m = 0; m < HIDDEN; ++m) t += hbuf[m] * sW2[m * NCLS + k];
            o[k] = dv * t;
        }
        float4* hp = (float4*)(hd2 + (size_t)node * NCLS);
        hp[0] = make_float4(o[0], o[1], o[2], o[3]);
        hp[1] = make_float4(o[4], o[5], o[6], o[7]);
    }
}

// layer2 aggregation in LDS + fused bias/log_softmax -> out
__global__ __launch_bounds__(1024) void k_aggC(const unsigned* __restrict__ hist,
                                               const unsigned* __restrict__ rec,
                                               const float* __restrict__ hd2,
                                               const float* __restrict__ dis,
                                               const float* __restrict__ b2,
                                               float* __restrict__ out) {
    __shared__ float acc[BSZ][NCLS + 1];    // 14.1 KB
    int tid = threadIdx.x;
    int bkt = blockIdx.x;
    int node0 = bkt * BSZ;
    int nn = (node0 + BSZ <= N_NODES) ? BSZ : (N_NODES - node0);

    int j = tid & 7, rr = tid >> 3;         // 128 edge-slots x 8 lanes
    for (int r = rr; r < nn; r += 128)
        acc[r][j] = hd2[(size_t)(node0 + r) * NCLS + j];     // self-loop init
    __syncthreads();

    unsigned start = hist[(unsigned)bkt * NCHUNK];
    unsigned end = (bkt == NBKT - 1) ? N_EDGES : hist[(unsigned)(bkt + 1) * NCHUNK];
    for (unsigned e = start + rr; e < end; e += 128) {
        unsigned r = rec[e];
        unsigned s = r >> 9, dl = r & 511u;
        atomicAdd(&acc[dl][j], hd2[(size_t)s * NCLS + j]);
    }
    __syncthreads();

    for (int n = tid; n < nn; n += 1024) {
        int node = node0 + n;
        float dv = dis[node];
        float l[NCLS];
        float m = -1e30f;
        #pragma unroll
        for (int k = 0; k < NCLS; ++k) {
            l[k] = dv * acc[n][k] + b2[k];
            m = fmaxf(m, l[k]);
        }
        float ssum = 0.f;
        #pragma unroll
        for (int k = 0; k < NCLS; ++k) ssum += __expf(l[k] - m);
        float lse = logf(ssum) + m;
        float4* op = (float4*)(out + (size_t)node * NCLS);
        op[0] = make_float4(l[0] - lse, l[1] - lse, l[2] - lse, l[3] - lse);
        op[1] = make_float4(l[4] - lse, l[5] - lse, l[6] - lse, l[7] - lse);
    }
}

extern "C" void kernel_launch(void* const* d_in, const int* in_sizes, int n_in,
                              void* d_out, int out_size, void* d_ws, size_t ws_size,
                              hipStream_t stream) {
    const float* x  = (const float*)d_in[0];
    const int*   ei = (const int*)d_in[1];      // [2, E]: row0 = src, row1 = dst
    const float* W1 = (const float*)d_in[2];
    const float* b1 = (const float*)d_in[3];
    const float* W2 = (const float*)d_in[4];
    const float* b2 = (const float*)d_in[5];
    float* out = (float*)d_out;

    const int* src = ei;
    const int* dst = ei + N_EDGES;

    unsigned* ws = (unsigned*)d_ws;
    const size_t N = N_NODES;
    float*    dis  = (float*)ws;
    unsigned* hist = ws + N;
    unsigned* bsum = hist + TOTH;
    unsigned* rec  = bsum + 512;
    float*    hd1  = (float*)(rec + N_EDGES);
    float*    hd2  = hd1 + 16 * N;

    k_hist <<<NCHUNK, 256, 0, stream>>>(dst, hist);
    k_scan1<<<NBS1, 256, 0, stream>>>(hist, bsum);
    k_scan2<<<1, 512, 0, stream>>>(bsum);
    k_scan3<<<NBS1, 256, 0, stream>>>(hist, bsum);
    k_fill <<<NCHUNK, 256, 0, stream>>>(src, dst, hist, rec);
    k_dis2 <<<NBKT, 1024, 0, stream>>>(hist, rec, dis);
    k_gemm1<<<(N_NODES + 63) / 64, 256, 0, stream>>>(x, W1, dis, hd1);
    k_aggB <<<NBKT, 1024, 0, stream>>>(hist, rec, hd1, dis, b1, W2, hd2);
    k_aggC <<<NBKT, 1024, 0, stream>>>(hist, rec, hd2, dis, b2, out);
}

// Round 4
// 576.003 us; speedup vs baseline: 1.2035x; 1.0380x over previous
//
#include <hip/hip_runtime.h>

#define N_NODES 100000
#define N_EDGES 3200000
#define D_FEAT 128
#define HIDDEN 16
#define NCLS 8

#define NBKT 512            // dst buckets
#define BSZ  196            // nodes per bucket (512*196 = 100352 >= 100000)
#define NSLICE 4            // edge-slice blocks per bucket
#define CHUNK 8192          // edges per hist/fill block
#define NCHUNK 391          // 391*8192 >= 3.2M
#define TOTH (NBKT * NCHUNK)   // 200192 = 782*256 exactly
#define NBS1 (TOTH / 256)      // 782

// -------- workspace layout (32-bit words) --------
// deg  (uint)  [0, N)
// dis  (float) [N, 2N)
// hist (uint)  [2N, +TOTH)     per (bucket,chunk) exclusive prefix starts
// bsum (uint)  [+1024)
// rec  (uint)  [+E)            (src<<8)|dst_local, bucketed by dst
// hd1  (float) [+16N)          dis * (x @ W1)
// agg1 (float) [+16N)
// hd2  (float) [+8N)           dis * (relu(dis*agg1+b1) @ W2)
// agg2 (float) [+8N)

__global__ void k_zero_deg(unsigned* __restrict__ deg) {
    int i = blockIdx.x * blockDim.x + threadIdx.x;
    if (i < N_NODES) deg[i] = 0u;
}

// per-chunk histogram of dst buckets
__global__ __launch_bounds__(256) void k_hist(const int* __restrict__ dst,
                                              unsigned* __restrict__ hist) {
    __shared__ unsigned h[NBKT];
    int tid = threadIdx.x;
    h[tid] = 0u; h[tid + 256] = 0u;
    __syncthreads();
    int base = blockIdx.x * CHUNK;
    #pragma unroll
    for (int it = 0; it < CHUNK / 256; ++it) {
        int e = base + it * 256 + tid;
        if (e < N_EDGES) atomicAdd(&h[dst[e] / BSZ], 1u);
    }
    __syncthreads();
    hist[(unsigned)tid * NCHUNK + blockIdx.x] = h[tid];
    hist[(unsigned)(tid + 256) * NCHUNK + blockIdx.x] = h[tid + 256];
}

// ---- exclusive prefix scan over hist (bucket-major flattened) ----
__global__ void k_scan1(unsigned* __restrict__ a, unsigned* __restrict__ bsum) {
    __shared__ unsigned s[256];
    int tid = threadIdx.x;
    int i = blockIdx.x * 256 + tid;
    unsigned v = a[i];                       // TOTH == grid*256 exactly
    s[tid] = v; __syncthreads();
    for (int off = 1; off < 256; off <<= 1) {
        unsigned t = (tid >= off) ? s[tid - off] : 0u;
        __syncthreads();
        s[tid] += t;
        __syncthreads();
    }
    a[i] = s[tid] - v;                       // exclusive
    if (tid == 255) bsum[blockIdx.x] = s[255];
}

__global__ void k_scan2(unsigned* __restrict__ bsum) {
    __shared__ unsigned s[1024];
    int tid = threadIdx.x;
    unsigned v = (tid < NBS1) ? bsum[tid] : 0u;
    s[tid] = v; __syncthreads();
    for (int off = 1; off < 1024; off <<= 1) {
        unsigned t = (tid >= off) ? s[tid - off] : 0u;
        __syncthreads();
        s[tid] += t;
        __syncthreads();
    }
    bsum[tid] = s[tid] - v;                  // exclusive
}

__global__ void k_scan3(unsigned* __restrict__ a, const unsigned* __restrict__ bsum) {
    int i = blockIdx.x * blockDim.x + threadIdx.x;
    a[i] += bsum[i >> 8];
}

// place packed edge records into exact slots; LDS cursors only
__global__ __launch_bounds__(256) void k_fill(const int* __restrict__ src,
                                              const int* __restrict__ dst,
                                              const unsigned* __restrict__ hist,
                                              unsigned* __restrict__ rec) {
    __shared__ unsigned cur[NBKT];
    int tid = threadIdx.x;
    cur[tid]       = hist[(unsigned)tid * NCHUNK + blockIdx.x];
    cur[tid + 256] = hist[(unsigned)(tid + 256) * NCHUNK + blockIdx.x];
    __syncthreads();
    int base = blockIdx.x * CHUNK;
    #pragma unroll
    for (int it = 0; it < CHUNK / 256; ++it) {
        int e = base + it * 256 + tid;
        if (e < N_EDGES) {
            int d = dst[e];
            int b = d / BSZ;
            unsigned p = atomicAdd(&cur[b], 1u);
            rec[p] = ((unsigned)src[e] << 8) | (unsigned)(d - b * BSZ);
        }
    }
}

// sliced per-bucket degree count (LDS) -> global atomic partial combine
__global__ __launch_bounds__(256) void k_deg(const unsigned* __restrict__ hist,
                                             const unsigned* __restrict__ rec,
                                             unsigned* __restrict__ deg) {
    __shared__ unsigned cnt[BSZ];
    int tid = threadIdx.x;
    int bkt = blockIdx.x >> 2, slice = blockIdx.x & 3;
    int node0 = bkt * BSZ;
    int nn = N_NODES - node0; if (nn > BSZ) nn = BSZ;
    if (nn <= 0) return;
    for (int n = tid; n < nn; n += 256) cnt[n] = 0u;
    __syncthreads();
    unsigned start = hist[(unsigned)bkt * NCHUNK];
    unsigned end = (bkt == NBKT - 1) ? N_EDGES : hist[(unsigned)(bkt + 1) * NCHUNK];
    for (unsigned e = start + slice * 256 + tid; e < end; e += 1024)
        atomicAdd(&cnt[rec[e] & 255u], 1u);
    __syncthreads();
    for (int n = tid; n < nn; n += 256)
        if (cnt[n]) atomicAdd(&deg[node0 + n], cnt[n]);
}

__global__ void k_disk(const unsigned* __restrict__ deg, float* __restrict__ dis) {
    int i = blockIdx.x * blockDim.x + threadIdx.x;
    if (i < N_NODES) dis[i] = rsqrtf((float)(deg[i] + 1u));   // +1 self-loop
}

// hd1 = dis[node] * (x @ W1); agg1 = hd1 (self-loop init)
__global__ __launch_bounds__(256) void k_gemm1(const float* __restrict__ x,
                                               const float* __restrict__ W1,
                                               const float* __restrict__ dis,
                                               float* __restrict__ hd1,
                                               float* __restrict__ agg1) {
    __shared__ float sW[D_FEAT * HIDDEN];   // 8 KB
    __shared__ float sx[64][132];
    int tid = threadIdx.x;
    for (int t = tid; t < D_FEAT * HIDDEN; t += 256) sW[t] = W1[t];

    int node0 = blockIdx.x * 64;
    #pragma unroll
    for (int it = 0; it < 8; ++it) {
        int lin = it * 256 + tid;
        int r   = lin >> 5;
        int c4  = lin & 31;
        int row = node0 + r;
        float4 v = make_float4(0.f, 0.f, 0.f, 0.f);
        if (row < N_NODES)
            v = *(const float4*)(x + (size_t)row * D_FEAT + c4 * 4);
        *(float4*)(&sx[r][c4 * 4]) = v;
    }
    __syncthreads();

    int lr   = tid >> 2;
    int node = node0 + lr;
    int f0   = (tid & 3) * 4;
    if (node >= N_NODES) return;

    float a0 = 0.f, a1 = 0.f, a2 = 0.f, a3 = 0.f;
    #pragma unroll
    for (int k = 0; k < D_FEAT; ++k) {
        float xv = sx[lr][k];
        a0 += xv * sW[k * HIDDEN + f0 + 0];
        a1 += xv * sW[k * HIDDEN + f0 + 1];
        a2 += xv * sW[k * HIDDEN + f0 + 2];
        a3 += xv * sW[k * HIDDEN + f0 + 3];
    }
    float s = dis[node];
    float4 o = make_float4(a0 * s, a1 * s, a2 * s, a3 * s);
    *(float4*)(hd1  + (size_t)node * HIDDEN + f0) = o;
    *(float4*)(agg1 + (size_t)node * HIDDEN + f0) = o;
}

// layer1 sliced gather-aggregate: LDS partial, combine via coalesced global atomics
__global__ __launch_bounds__(256) void k_agg1(const unsigned* __restrict__ hist,
                                              const unsigned* __restrict__ rec,
                                              const float* __restrict__ hd1,
                                              float* __restrict__ agg1) {
    __shared__ float acc[BSZ][HIDDEN + 1];  // 13.3 KB
    int tid = threadIdx.x;
    int bkt = blockIdx.x >> 2, slice = blockIdx.x & 3;
    int node0 = bkt * BSZ;
    int nn = N_NODES - node0; if (nn > BSZ) nn = BSZ;
    if (nn <= 0) return;
    for (int t = tid; t < nn * HIDDEN; t += 256) acc[t >> 4][t & 15] = 0.f;
    __syncthreads();

    unsigned start = hist[(unsigned)bkt * NCHUNK];
    unsigned end = (bkt == NBKT - 1) ? N_EDGES : hist[(unsigned)(bkt + 1) * NCHUNK];
    int j = tid & 15, rr = tid >> 4;        // 16 edge slots x 16 feat lanes
    unsigned e = start + (unsigned)(slice * 16 + rr);
    for (; e + 192u < end; e += 256u) {     // 4 independent gathers in flight
        unsigned r0 = rec[e], r1 = rec[e + 64u], r2 = rec[e + 128u], r3 = rec[e + 192u];
        float v0 = hd1[(size_t)(r0 >> 8) * HIDDEN + j];
        float v1 = hd1[(size_t)(r1 >> 8) * HIDDEN + j];
        float v2 = hd1[(size_t)(r2 >> 8) * HIDDEN + j];
        float v3 = hd1[(size_t)(r3 >> 8) * HIDDEN + j];
        atomicAdd(&acc[r0 & 255u][j], v0);
        atomicAdd(&acc[r1 & 255u][j], v1);
        atomicAdd(&acc[r2 & 255u][j], v2);
        atomicAdd(&acc[r3 & 255u][j], v3);
    }
    for (; e < end; e += 64u) {
        unsigned r = rec[e];
        atomicAdd(&acc[r & 255u][j], hd1[(size_t)(r >> 8) * HIDDEN + j]);
    }
    __syncthreads();
    for (int t = tid; t < nn * HIDDEN; t += 256) {
        float v = acc[t >> 4][t & 15];
        if (v != 0.f) atomicAdd(&agg1[(size_t)node0 * HIDDEN + t], v);
    }
}

// epilogue 1: h = relu(dis*agg1 + b1); hd2 = dis*(h @ W2); agg2 = hd2
__global__ __launch_bounds__(256) void k_epi1(const float* __restrict__ agg1,
                                              const float* __restrict__ dis,
                                              const float* __restrict__ b1,
                                              const float* __restrict__ W2,
                                              float* __restrict__ hd2,
                                              float* __restrict__ agg2) {
    __shared__ float sW2[HIDDEN * NCLS];
    __shared__ float sb1[HIDDEN];
    int tid = threadIdx.x;
    if (tid < HIDDEN * NCLS) sW2[tid] = W2[tid];
    if (tid < HIDDEN)        sb1[tid] = b1[tid];
    __syncthreads();
    int i = blockIdx.x * 256 + tid;
    if (i >= N_NODES) return;
    float dv = dis[i];
    float h[HIDDEN];
    const float4* ap = (const float4*)(agg1 + (size_t)i * HIDDEN);
    #pragma unroll
    for (int q = 0; q < 4; ++q) {
        float4 a = ap[q];
        h[q * 4 + 0] = fmaxf(dv * a.x + sb1[q * 4 + 0], 0.f);
        h[q * 4 + 1] = fmaxf(dv * a.y + sb1[q * 4 + 1], 0.f);
        h[q * 4 + 2] = fmaxf(dv * a.z + sb1[q * 4 + 2], 0.f);
        h[q * 4 + 3] = fmaxf(dv * a.w + sb1[q * 4 + 3], 0.f);
    }
    float o[NCLS];
    #pragma unroll
    for (int k = 0; k < NCLS; ++k) o[k] = 0.f;
    #pragma unroll
    for (int m = 0; m < HIDDEN; ++m) {
        float hv = h[m];
        #pragma unroll
        for (int k = 0; k < NCLS; ++k) o[k] += hv * sW2[m * NCLS + k];
    }
    float4 o0 = make_float4(dv * o[0], dv * o[1], dv * o[2], dv * o[3]);
    float4 o1 = make_float4(dv * o[4], dv * o[5], dv * o[6], dv * o[7]);
    ((float4*)(hd2  + (size_t)i * NCLS))[0] = o0;
    ((float4*)(hd2  + (size_t)i * NCLS))[1] = o1;
    ((float4*)(agg2 + (size_t)i * NCLS))[0] = o0;
    ((float4*)(agg2 + (size_t)i * NCLS))[1] = o1;
}

// layer2 sliced gather-aggregate
__global__ __launch_bounds__(256) void k_agg2(const unsigned* __restrict__ hist,
                                              const unsigned* __restrict__ rec,
                                              const float* __restrict__ hd2,
                                              float* __restrict__ agg2) {
    __shared__ float acc[BSZ][NCLS + 1];    // 7 KB
    int tid = threadIdx.x;
    int bkt = blockIdx.x >> 2, slice = blockIdx.x & 3;
    int node0 = bkt * BSZ;
    int nn = N_NODES - node0; if (nn > BSZ) nn = BSZ;
    if (nn <= 0) return;
    for (int t = tid; t < nn * NCLS; t += 256) acc[t >> 3][t & 7] = 0.f;
    __syncthreads();

    unsigned start = hist[(unsigned)bkt * NCHUNK];
    unsigned end = (bkt == NBKT - 1) ? N_EDGES : hist[(unsigned)(bkt + 1) * NCHUNK];
    int j = tid & 7, rr = tid >> 3;         // 32 edge slots x 8 lanes
    unsigned e = start + (unsigned)(slice * 32 + rr);
    for (; e + 384u < end; e += 512u) {
        unsigned r0 = rec[e], r1 = rec[e + 128u], r2 = rec[e + 256u], r3 = rec[e + 384u];
        float v0 = hd2[(size_t)(r0 >> 8) * NCLS + j];
        float v1 = hd2[(size_t)(r1 >> 8) * NCLS + j];
        float v2 = hd2[(size_t)(r2 >> 8) * NCLS + j];
        float v3 = hd2[(size_t)(r3 >> 8) * NCLS + j];
        atomicAdd(&acc[r0 & 255u][j], v0);
        atomicAdd(&acc[r1 & 255u][j], v1);
        atomicAdd(&acc[r2 & 255u][j], v2);
        atomicAdd(&acc[r3 & 255u][j], v3);
    }
    for (; e < end; e += 128u) {
        unsigned r = rec[e];
        atomicAdd(&acc[r & 255u][j], hd2[(size_t)(r >> 8) * NCLS + j]);
    }
    __syncthreads();
    for (int t = tid; t < nn * NCLS; t += 256) {
        float v = acc[t >> 3][t & 7];
        if (v != 0.f) atomicAdd(&agg2[(size_t)node0 * NCLS + t], v);
    }
}

// epilogue 2: logits = dis*agg2 + b2 -> log_softmax
__global__ void k_epi2(const float* __restrict__ agg2, const float* __restrict__ dis,
                       const float* __restrict__ b2, float* __restrict__ out) {
    int i = blockIdx.x * blockDim.x + threadIdx.x;
    if (i >= N_NODES) return;
    float dv = dis[i];
    const float4* ap = (const float4*)(agg2 + (size_t)i * NCLS);
    float4 a0 = ap[0], a1 = ap[1];
    float l[NCLS];
    l[0] = dv * a0.x + b2[0]; l[1] = dv * a0.y + b2[1];
    l[2] = dv * a0.z + b2[2]; l[3] = dv * a0.w + b2[3];
    l[4] = dv * a1.x + b2[4]; l[5] = dv * a1.y + b2[5];
    l[6] = dv * a1.z + b2[6]; l[7] = dv * a1.w + b2[7];
    float m = l[0];
    #pragma unroll
    for (int k = 1; k < NCLS; ++k) m = fmaxf(m, l[k]);
    float ssum = 0.f;
    #pragma unroll
    for (int k = 0; k < NCLS; ++k) ssum += __expf(l[k] - m);
    float lse = logf(ssum) + m;
    float4* op = (float4*)(out + (size_t)i * NCLS);
    op[0] = make_float4(l[0] - lse, l[1] - lse, l[2] - lse, l[3] - lse);
    op[1] = make_float4(l[4] - lse, l[5] - lse, l[6] - lse, l[7] - lse);
}

extern "C" void kernel_launch(void* const* d_in, const int* in_sizes, int n_in,
                              void* d_out, int out_size, void* d_ws, size_t ws_size,
                              hipStream_t stream) {
    const float* x  = (const float*)d_in[0];
    const int*   ei = (const int*)d_in[1];      // [2, E]
    const float* W1 = (const float*)d_in[2];
    const float* b1 = (const float*)d_in[3];
    const float* W2 = (const float*)d_in[4];
    const float* b2 = (const float*)d_in[5];
    float* out = (float*)d_out;

    const int* src = ei;
    const int* dst = ei + N_EDGES;

    unsigned* ws = (unsigned*)d_ws;
    const size_t N = N_NODES;
    unsigned* deg  = ws;
    float*    dis  = (float*)(ws + N);
    unsigned* hist = ws + 2 * N;
    unsigned* bsum = hist + TOTH;
    unsigned* rec  = bsum + 1024;
    float*    hd1  = (float*)(rec + N_EDGES);
    float*    agg1 = hd1 + 16 * N;
    float*    hd2  = agg1 + 16 * N;
    float*    agg2 = hd2 + 8 * N;

    int nbN = (N_NODES + 255) / 256;   // 391

    k_zero_deg<<<nbN, 256, 0, stream>>>(deg);
    k_hist <<<NCHUNK, 256, 0, stream>>>(dst, hist);
    k_scan1<<<NBS1, 256, 0, stream>>>(hist, bsum);
    k_scan2<<<1, 1024, 0, stream>>>(bsum);
    k_scan3<<<NBS1, 256, 0, stream>>>(hist, bsum);
    k_fill <<<NCHUNK, 256, 0, stream>>>(src, dst, hist, rec);
    k_deg  <<<NBKT * NSLICE, 256, 0, stream>>>(hist, rec, deg);
    k_disk <<<nbN, 256, 0, stream>>>(deg, dis);
    k_gemm1<<<(N_NODES + 63) / 64, 256, 0, stream>>>(x, W1, dis, hd1, agg1);
    k_agg1 <<<NBKT * NSLICE, 256, 0, stream>>>(hist, rec, hd1, agg1);
    k_epi1 <<<nbN, 256, 0, stream>>>(agg1, dis, b1, W2, hd2, agg2);
    k_agg2 <<<NBKT * NSLICE, 256, 0, stream>>>(hist, rec, hd2, agg2);
    k_epi2 <<<nbN, 256, 0, stream>>>(agg2, dis, b2, out);
}